// Round 7
// baseline (365.929 us; speedup 1.0000x reference)
//
#include <hip/hip_runtime.h>
#include <cstdint>
#include <cstddef>

#define AS1 __attribute__((address_space(1)))
#define AS3 __attribute__((address_space(3)))

typedef float f32x4 __attribute__((ext_vector_type(4)));
typedef __bf16 bf16x8 __attribute__((ext_vector_type(8)));
typedef __bf16 bf16x4 __attribute__((ext_vector_type(4)));
typedef uint32_t u32x4 __attribute__((ext_vector_type(4)));

// async global->LDS, 16B per lane. LDS dest = wave-uniform base + lane*16.
__device__ __forceinline__ void async_cp16(void* lds, const void* g) {
    __builtin_amdgcn_global_load_lds((AS1 void*)(g), (AS3 void*)(lds), 16, 0, 0);
}

__device__ __forceinline__ bf16x8 frag_of(u32x4 u) {
    return __builtin_bit_cast(bf16x8, u);
}

// ---------------------------------------------------------------- weight cvt
// qkv_w rows permuted from interleaved (h,{q,k,v},d) to [q(768)|k(768)|v(768)]
__global__ __launch_bounds__(256)
void cvt_w(const float* __restrict__ qkvw, const float* __restrict__ projw,
           __bf16* __restrict__ qkvwb, __bf16* __restrict__ projwb) {
    int i = blockIdx.x * 256 + threadIdx.x;   // grid 2304*256 = 589824 exactly
    if (i < 442368) {                          // 2304 rows x 192 float4
        int row = i / 192, c4 = (i - row * 192) * 4;
        int t = (row >= 1536) ? 2 : (row >= 768 ? 1 : 0);
        int rem = row - t * 768;
        int hh = rem >> 6, d = rem & 63;
        int in_row = hh * 192 + t * 64 + d;
        float4 v = *(const float4*)(qkvw + (long)in_row * 768 + c4);
        bf16x4 o;
        o[0] = (__bf16)v.x; o[1] = (__bf16)v.y; o[2] = (__bf16)v.z; o[3] = (__bf16)v.w;
        *(bf16x4*)(qkvwb + (long)row * 768 + c4) = o;
    } else {
        int j = i - 442368;                    // 147456 float4 of proj_w
        float4 v = ((const float4*)projw)[j];
        bf16x4 o;
        o[0] = (__bf16)v.x; o[1] = (__bf16)v.y; o[2] = (__bf16)v.z; o[3] = (__bf16)v.w;
        ((bf16x4*)projwb)[j] = o;
    }
}

// ---------------------------------------------------------------- LayerNorm
__global__ __launch_bounds__(256)
void ln_kernel(const float* __restrict__ x, const float* __restrict__ w,
               const float* __restrict__ bsh, __bf16* __restrict__ xn) {
    const int lane = threadIdx.x & 63;
    const long row = (long)blockIdx.x * 4 + (threadIdx.x >> 6);
    const float4* xr = (const float4*)(x + row * 768);
    float4 v[3];
    v[0] = xr[lane]; v[1] = xr[lane + 64]; v[2] = xr[lane + 128];
    float s = 0.f, ss = 0.f;
#pragma unroll
    for (int i = 0; i < 3; ++i) {
        s  += v[i].x + v[i].y + v[i].z + v[i].w;
        ss += v[i].x * v[i].x + v[i].y * v[i].y + v[i].z * v[i].z + v[i].w * v[i].w;
    }
#pragma unroll
    for (int m = 1; m < 64; m <<= 1) { s += __shfl_xor(s, m); ss += __shfl_xor(ss, m); }
    const float mean = s * (1.f / 768.f);
    const float rstd = rsqrtf(ss * (1.f / 768.f) - mean * mean + 1e-5f);
    const float4* wv = (const float4*)w;
    const float4* bv = (const float4*)bsh;
    bf16x4* outp = (bf16x4*)(xn + row * 768);
#pragma unroll
    for (int i = 0; i < 3; ++i) {
        float4 wi = wv[lane + 64 * i], bi = bv[lane + 64 * i];
        bf16x4 o;
        o[0] = (__bf16)((v[i].x - mean) * rstd * wi.x + bi.x);
        o[1] = (__bf16)((v[i].y - mean) * rstd * wi.y + bi.y);
        o[2] = (__bf16)((v[i].z - mean) * rstd * wi.z + bi.z);
        o[3] = (__bf16)((v[i].w - mean) * rstd * wi.w + bi.w);
        outp[lane + 64 * i] = o;
    }
}

// ---------------------------------------------------------------- GEMM core
// 128x128 tile, BK=32, 4 waves. A staged in ring-3 LDS (24KB); B-frags loaded
// DIRECTLY from global (L2-hot 3.5MB weight panel) into registers via inline
// asm, double-buffered 2 K-steps ahead -> per kstep only 4 ds_read_b128 and
// B is already in registers when the barrier opens (halves the post-barrier
// LDS-latency chain that capped MfmaUtil at 26%). Counted vmcnt(6) =
// {A(t+1):2cp16 + B(t+1):4loads} in flight; sched_barrier(0) after every
// waitcnt (compiler would otherwise hoist MFMAs above the asm wait).
// A frag reads XOR-swizzled (swq), inverse swizzle on the staged source.
// MODE 0: qk cols, swapped mfma -> packed (b,h,n,d) stores.
// MODE 2: v cols, normal mfma -> packed V^T (b,h,d,n) stores.
// MODE 1: proj, normal mfma -> fp32 out.
template <int MODE>
__device__ __forceinline__
void gemm_core(char* smem,
               const __bf16* __restrict__ A, const __bf16* __restrict__ Bw,
               const float* __restrict__ bias,
               __bf16* __restrict__ q_out, __bf16* __restrict__ k_out,
               __bf16* __restrict__ vt_out, float* __restrict__ f_out,
               long bm, long bn) {
    constexpr int K = 768;
    const int tid  = threadIdx.x;
    const int lane = tid & 63;
    const int quad = lane >> 4;
    const int l16  = lane & 15;
    const int wave = tid >> 6;
    const int wm = wave >> 1, wn = wave & 1;

    const __bf16* Ab = A  + bm * K;
    const __bf16* Bb = Bw + bn * K;

    const int e0 = tid, e1 = tid + 256;
    const int rA0 = e0 >> 2, cA0 = ((e0 & 3) ^ ((e0 >> 3) & 3)) * 8;
    const int rA1 = e1 >> 2, cA1 = ((e1 & 3) ^ ((e1 >> 3) & 3)) * 8;
    const int swq = quad ^ ((l16 >> 1) & 3);

    f32x4 acc[4][4] = {};

    // B direct-load pointers (row = output col, 16B per lane at k-chunk quad)
    const __bf16* bp0 = Bb + (long)(wn * 64 +  0 + l16) * K + quad * 8;
    const __bf16* bp1 = Bb + (long)(wn * 64 + 16 + l16) * K + quad * 8;
    const __bf16* bp2 = Bb + (long)(wn * 64 + 32 + l16) * K + quad * 8;
    const __bf16* bp3 = Bb + (long)(wn * 64 + 48 + l16) * K + quad * 8;
    u32x4 bsA[4], bsB[4];

    const __bf16* Asrc = Ab;          // next A k-slab to stage
    char* sstage = smem;              // ring-3 stage dest
    char* sread  = smem;              // ring-3 compute src

    auto stageA = [&]() {
        async_cp16(sstage + e0 * 16, Asrc + (long)rA0 * K + cA0);
        async_cp16(sstage + e1 * 16, Asrc + (long)rA1 * K + cA1);
        Asrc += 32;
        sstage += 8192; if (sstage == smem + 24576) sstage = smem;
    };

    auto kstep = [&](u32x4 (&bs)[4]) {
        const u32x4* Av = (const u32x4*)sread;
        bf16x8 af[4];
#pragma unroll
        for (int t = 0; t < 4; ++t)
            af[t] = frag_of(Av[(wm * 64 + t * 16 + l16) * 4 + swq]);
        __builtin_amdgcn_s_setprio(1);
#pragma unroll
        for (int i = 0; i < 4; ++i)
#pragma unroll
            for (int j = 0; j < 4; ++j) {
                if constexpr (MODE == 0)
                    acc[i][j] = __builtin_amdgcn_mfma_f32_16x16x32_bf16(frag_of(bs[j]), af[i], acc[i][j], 0, 0, 0);
                else
                    acc[i][j] = __builtin_amdgcn_mfma_f32_16x16x32_bf16(af[i], frag_of(bs[j]), acc[i][j], 0, 0, 0);
            }
        __builtin_amdgcn_s_setprio(0);
        sread += 8192; if (sread == smem + 24576) sread = smem;
    };

    auto bload = [&](u32x4 (&bs)[4]) {
        asm volatile("global_load_dwordx4 %0, %1, off" : "=v"(bs[0]) : "v"(bp0) : "memory");
        asm volatile("global_load_dwordx4 %0, %1, off" : "=v"(bs[1]) : "v"(bp1) : "memory");
        asm volatile("global_load_dwordx4 %0, %1, off" : "=v"(bs[2]) : "v"(bp2) : "memory");
        asm volatile("global_load_dwordx4 %0, %1, off" : "=v"(bs[3]) : "v"(bp3) : "memory");
        bp0 += 32; bp1 += 32; bp2 += 32; bp3 += 32;
    };

    // prologue: A(0),B(0),A(1),B(1) in flight (6 ops after first pair retires)
    stageA(); bload(bsA);
    stageA(); bload(bsB);

    for (int t2 = 0; t2 < 12; ++t2) {
        // even iter t = 2*t2 (uses bsA); t <= 22 so A(t),B(t) retire at vmcnt(6)
        asm volatile("s_waitcnt vmcnt(6)" ::: "memory");
        __builtin_amdgcn_sched_barrier(0);
        __builtin_amdgcn_s_barrier();
        if (t2 < 11) stageA();        // A(t+2)
        kstep(bsA);                   // consumes A(t) LDS + B(t) regs
        if (t2 < 11) bload(bsA);      // B(t+2) into the set just consumed

        // odd iter t = 2*t2+1 (uses bsB); t=23 must drain fully
        if (t2 < 11) { asm volatile("s_waitcnt vmcnt(6)" ::: "memory"); }
        else         { asm volatile("s_waitcnt vmcnt(0)" ::: "memory"); }
        __builtin_amdgcn_sched_barrier(0);
        __builtin_amdgcn_s_barrier();
        if (t2 < 11) stageA();
        kstep(bsB);
        if (t2 < 11) bload(bsB);
    }

    if constexpr (MODE == 0) {
        // swapped: lane row = n (l16-based), 4 consecutive cols per quad
#pragma unroll
        for (int j = 0; j < 4; ++j) {
            int col0 = (int)bn + wn * 64 + j * 16 + quad * 4;   // < 1536
            int t  = col0 >= 768;
            int cc = col0 - t * 768;
            int h  = cc >> 6, d = cc & 63;
            int f  = h * 192 + t * 64 + d;                      // original feature id
            float4 bb = *(const float4*)(bias + f);
            __bf16* dst = t ? k_out : q_out;
#pragma unroll
            for (int i = 0; i < 4; ++i) {
                long row = bm + wm * 64 + i * 16 + l16;
                long b   = row >> 10;
                long n   = row & 1023;
                bf16x4 pk;
                pk[0] = (__bf16)(acc[i][j][0] + bb.x);
                pk[1] = (__bf16)(acc[i][j][1] + bb.y);
                pk[2] = (__bf16)(acc[i][j][2] + bb.z);
                pk[3] = (__bf16)(acc[i][j][3] + bb.w);
                *(bf16x4*)(dst + ((b * 12 + h) * 1024 + n) * 64 + d) = pk;
            }
        }
    } else if constexpr (MODE == 2) {
        // normal: lane col = d (l16-based), 4 consecutive rows (n) per quad
#pragma unroll
        for (int j = 0; j < 4; ++j) {
            int cv = (int)bn - 1536 + wn * 64 + j * 16 + l16;
            int h  = cv >> 6, d = cv & 63;
            float bv = bias[h * 192 + 128 + d];
#pragma unroll
            for (int i = 0; i < 4; ++i) {
                long row0 = bm + wm * 64 + i * 16 + quad * 4;
                long b    = row0 >> 10;
                long n0   = row0 & 1023;
                bf16x4 pk;
                pk[0] = (__bf16)(acc[i][j][0] + bv);
                pk[1] = (__bf16)(acc[i][j][1] + bv);
                pk[2] = (__bf16)(acc[i][j][2] + bv);
                pk[3] = (__bf16)(acc[i][j][3] + bv);
                *(bf16x4*)(vt_out + ((b * 12 + h) * 64 + d) * 1024 + n0) = pk;
            }
        }
    } else {
#pragma unroll
        for (int i = 0; i < 4; ++i) {
#pragma unroll
            for (int r = 0; r < 4; ++r) {
                long row = bm + wm * 64 + i * 16 + quad * 4 + r;
#pragma unroll
                for (int j = 0; j < 4; ++j) {
                    int col = (int)bn + wn * 64 + j * 16 + l16;
                    f_out[row * 768 + col] = acc[i][j][r] + bias[col];
                }
            }
        }
    }
}

// XCD-aware decode: all blocks sharing one A-tile (by) land on one XCD.
__global__ __launch_bounds__(256, 3)
void gemm_qkv(const __bf16* __restrict__ A, const __bf16* __restrict__ Bw,
              const float* __restrict__ bias, __bf16* __restrict__ qb,
              __bf16* __restrict__ kb, __bf16* __restrict__ vtb) {
    __shared__ __align__(16) char smem[24576];   // ring-3 x A 8K
    int blk  = blockIdx.x;            // grid 2304 = 3 exact rounds at 3 blocks/CU
    int xcd  = blk & 7;
    int rest = blk >> 3;              // 0..287
    int bx   = rest % 18;
    int byg  = rest / 18;             // 0..15
    long by  = xcd + 8 * byg;         // by % 8 == xcd
    if (bx < 12)
        gemm_core<0>(smem, A, Bw, bias, qb, kb, nullptr, nullptr, by * 128, (long)bx * 128);
    else
        gemm_core<2>(smem, A, Bw, bias, nullptr, nullptr, vtb, nullptr, by * 128, (long)bx * 128);
}

__global__ __launch_bounds__(256, 3)
void gemm_proj(const __bf16* __restrict__ A, const __bf16* __restrict__ Bw,
               const float* __restrict__ bias, float* __restrict__ out) {
    __shared__ __align__(16) char smem[24576];
    int blk  = blockIdx.x;            // grid 768 = exactly 1 round at 3 blocks/CU
    int xcd  = blk & 7;
    int rest = blk >> 3;              // 0..95
    int bx   = rest % 6;
    int byg  = rest / 6;              // 0..15
    long by  = xcd + 8 * byg;
    gemm_core<1>(smem, A, Bw, bias, nullptr, nullptr, nullptr, out,
                 by * 128, (long)bx * 128);
}

// ---------------------------------------------------------------- flash attention
// 256 thr / 4 waves, 128-row q-tile, 32 q-rows/wave (g=0,1 groups, K/V frag
// reuse across g). KVBLK=32: one k-tile = exactly one y-row (dy wave-uniform).
// LDS = 28KB (K dbuf 8K + V^T dbuf 8K + P 8K + bias 4K).
// Row widths chosen for bank-freedom: K/Q rows 128B (8 slots, sw=l16&7);
// P/V rows 64B with chunk swizzle rho(row)=(row>>1)&3 -> every b128 read and
// b64 write lands 2 lanes/bank (free). P goes through LDS.
// K/V double-buffered; prefetch kt+1 before compute kt; ONE barrier per tile.
__global__ __launch_bounds__(256, 4)
void attn_kernel(const __bf16* __restrict__ Q, const __bf16* __restrict__ Kb,
                 const __bf16* __restrict__ Vt, const float* __restrict__ biases,
                 __bf16* __restrict__ out) {
    // [0,8K): K dbuf 2x4K | [8K,16K): V^T dbuf 2x4K | [16K,24K): P per-wave 2K
    // [24K,28K): bias row f32 * log2(e).  Q stages through [0,16K) at startup.
    __shared__ __align__(16) char smem[28672];
    float* brow = (float*)(smem + 24576);

    const int tid  = threadIdx.x;
    const int lane = tid & 63;
    const int wave = tid >> 6;        // 0..3
    const int quad = lane >> 4;
    const int l16  = lane & 15;
    const int sw   = l16 & 7;         // 8-slot rows (Q, K)
    const int swp  = (l16 >> 1) & 3;  // 4-slot rows (P, V)

    int blk  = blockIdx.x;            // grid 1536
    int xcd  = blk & 7;
    int rest = blk >> 3;              // 0..191
    int qt   = rest & 7;              // 0..7 (128-row q tiles)
    int bhg  = rest >> 3;             // 0..23
    int bh_i = xcd + 8 * bhg;         // 0..191, bh % 8 == xcd
    int b    = bh_i / 12;
    int h    = bh_i - b * 12;

    const long bh = bh_i;
    const __bf16* Qg  = Q  + (bh * 1024 + qt * 128) * 64;
    const __bf16* Kg  = Kb + bh * 1024 * 64;
    const __bf16* Vtg = Vt + bh * 64 * 1024;

    // staging indices (kt-invariant)
    const int rk = tid >> 3;                    // K: row 0..31 (128B rows)
    const int ck = (tid & 7) ^ (rk & 7);
    const int rv = tid >> 2;                    // V: row 0..63 (64B rows)
    const int cv = (tid & 3) ^ ((tid >> 3) & 3);

    // prologue: bias row + Q (through K/V region) -------------------------
    {
        const float LOG2E = 1.4426950408889634f;
        float4 v = ((const float4*)(biases + (long)h * 1024))[tid];
        float4 o; o.x = v.x * LOG2E; o.y = v.y * LOG2E;
        o.z = v.z * LOG2E; o.w = v.w * LOG2E;
        ((float4*)brow)[tid] = o;
    }
#pragma unroll
    for (int j = 0; j < 4; ++j) {
        int e = tid + 256 * j;
        int r = e >> 3, c = (e & 7) ^ (r & 7);
        async_cp16(smem + e * 16, Qg + r * 64 + c * 8);
    }
    __syncthreads();                  // Q resident (barrier drains vmcnt)

    bf16x8 aq[2][2];
    {
        const u32x4* Qv = (const u32x4*)smem;
#pragma unroll
        for (int g = 0; g < 2; ++g) {
            int qrow = wave * 32 + g * 16 + l16;
            aq[g][0] = frag_of(Qv[qrow * 8 + (quad ^ sw)]);
            aq[g][1] = frag_of(Qv[qrow * 8 + ((quad + 4) ^ sw)]);
        }
    }
    __syncthreads();                  // all waves done reading Q
    async_cp16(smem + tid * 16,        Kg  + rk * 64   + ck * 8);   // K0
    async_cp16(smem + 8192 + tid * 16, Vtg + rv * 1024 + cv * 8);   // V0
    __syncthreads();                  // K0/V0 resident

    // relative-position tables (kt-invariant); g==nt -> pdx00, g<nt -> pdx01,
    // g>nt -> pdx10
    const int yq = 4 * qt + wave;
    int pdx00[4], pdx01[4], pdx10[4];
#pragma unroll
    for (int r = 0; r < 4; ++r) {
        int d0 = l16 - (quad * 4 + r);
        pdx00[r] = d0 < 0 ? -d0 : d0;
        pdx01[r] = 16 - d0;
        pdx10[r] = 16 + d0;
    }

    const float SSCALE = 0.125f * 1.4426950408889634f;
    float lacc[2] = {0.f, 0.f};
    f32x4 o[2][4] = {};
    char* Pw = smem + 16384 + wave * 2048;      // 32 rows x 64B, per-wave
    const int hb = (quad & 1) * 8;
    const int pslotw = (quad >> 1);             // write chunk sub-index base

    for (int kt = 0; kt < 32; ++kt) {
        const int cb = kt & 1;
        if (kt < 31) {
            const int nb = cb ^ 1;
            async_cp16(smem + nb * 4096 + tid * 16,
                       Kg + (kt + 1) * 2048 + rk * 64 + ck * 8);
            async_cp16(smem + 8192 + nb * 4096 + tid * 16,
                       Vtg + (kt + 1) * 32 + rv * 1024 + cv * 8);
        }

        // S^T = K * Q^T : s[g][nt][r] = S[q=g*16+l16][k = kt*32+nt*16+quad*4+r]
        f32x4 s[2][2];
        const u32x4* Kv = (const u32x4*)(smem + cb * 4096);
#pragma unroll
        for (int nt = 0; nt < 2; ++nt) {
            int krow = nt * 16 + l16;
            bf16x8 k0 = frag_of(Kv[krow * 8 + (quad ^ sw)]);
            bf16x8 k1 = frag_of(Kv[krow * 8 + ((quad + 4) ^ sw)]);
#pragma unroll
            for (int g = 0; g < 2; ++g) {
                f32x4 z = {0.f, 0.f, 0.f, 0.f};
                z = __builtin_amdgcn_mfma_f32_16x16x32_bf16(k0, aq[g][0], z, 0, 0, 0);
                z = __builtin_amdgcn_mfma_f32_16x16x32_bf16(k1, aq[g][1], z, 0, 0, 0);
                s[g][nt] = z;
            }
        }

        // softmax + P store (per-wave LDS, rho-swizzled 64B rows)
        int dyv = yq - kt; dyv = dyv < 0 ? -dyv : dyv;
        const float* br = brow + dyv * 32;
#pragma unroll
        for (int g = 0; g < 2; ++g) {
#pragma unroll
            for (int nt = 0; nt < 2; ++nt) {
                const int* pdx = (g == nt) ? pdx00 : (g ? pdx10 : pdx01);
                bf16x4 pk;
#pragma unroll
                for (int r = 0; r < 4; ++r) {
                    float p = __builtin_amdgcn_exp2f(s[g][nt][r] * SSCALE + br[pdx[r]]);
                    lacc[g] += p;
                    pk[r] = (__bf16)p;
                }
                int slot = (nt * 2 + pslotw) ^ swp;
                *(bf16x4*)(Pw + (g * 16 + l16) * 64 + slot * 16 + hb) = pk;
            }
        }

        // P read (B-frags) + O^T = V^T * P^T
        bf16x8 bp[2];
#pragma unroll
        for (int g = 0; g < 2; ++g)
            bp[g] = frag_of(*(const u32x4*)(Pw + (g * 16 + l16) * 64 + ((quad ^ swp) << 4)));
        const char* Vb = smem + 8192 + cb * 4096;
#pragma unroll
        for (int dt = 0; dt < 4; ++dt) {
            bf16x8 vf = frag_of(*(const u32x4*)(Vb + (dt * 16 + l16) * 64 + ((quad ^ swp) << 4)));
#pragma unroll
            for (int g = 0; g < 2; ++g)
                o[g][dt] = __builtin_amdgcn_mfma_f32_16x16x32_bf16(vf, bp[g], o[g][dt], 0, 0, 0);
        }

        // single barrier per tile: drains prefetch (vmcnt) AFTER compute and
        // protects buffer cb from being overwritten next iteration
        __syncthreads();
    }

    // deferred row-sum: combine the 4 quads holding the same q-row
#pragma unroll
    for (int g = 0; g < 2; ++g) {
        float la = lacc[g];
        la += __shfl_xor(la, 16);
        la += __shfl_xor(la, 32);
        const float rl = 1.f / la;
        const long n = qt * 128 + wave * 32 + g * 16 + l16;
        __bf16* op = out + ((long)b * 1024 + n) * 768 + h * 64 + quad * 4;
#pragma unroll
        for (int dt = 0; dt < 4; ++dt) {
            bf16x4 ov;
            ov[0] = (__bf16)(o[g][dt][0] * rl);
            ov[1] = (__bf16)(o[g][dt][1] * rl);
            ov[2] = (__bf16)(o[g][dt][2] * rl);
            ov[3] = (__bf16)(o[g][dt][3] * rl);
            *(bf16x4*)(op + dt * 16) = ov;
        }
    }
}

// ---------------------------------------------------------------- launch
extern "C" void kernel_launch(void* const* d_in, const int* in_sizes, int n_in,
                              void* d_out, int out_size, void* d_ws, size_t ws_size,
                              hipStream_t stream) {
    (void)in_sizes; (void)n_in; (void)out_size; (void)ws_size;
    const float* x      = (const float*)d_in[0];
    const float* ln_w   = (const float*)d_in[1];
    const float* ln_b   = (const float*)d_in[2];
    const float* qkv_w  = (const float*)d_in[3];
    const float* qkv_b  = (const float*)d_in[4];
    const float* proj_w = (const float*)d_in[5];
    const float* proj_b = (const float*)d_in[6];
    const float* ab     = (const float*)d_in[7];
    float* outp = (float*)d_out;

    char* ws = (char*)d_ws;
    __bf16* xn     = (__bf16*)(ws);               // reused as attn output
    __bf16* aout   = (__bf16*)(ws);
    __bf16* qkvwb  = (__bf16*)(ws + 25165824);
    __bf16* projwb = (__bf16*)(ws + 28704768);
    __bf16* qb     = (__bf16*)(ws + 29884416);
    __bf16* kb     = (__bf16*)(ws + 55050240);
    __bf16* vtb    = (__bf16*)(ws + 80216064);    // V^T (b,h,d,n), direct from GEMM

    cvt_w<<<2304, 256, 0, stream>>>(qkv_w, proj_w, qkvwb, projwb);
    ln_kernel<<<4096, 256, 0, stream>>>(x, ln_w, ln_b, xn);
    gemm_qkv<<<2304, 256, 0, stream>>>(xn, qkvwb, qkv_b, qb, kb, vtb);
    attn_kernel<<<1536, 256, 0, stream>>>(qb, kb, vtb, ab, aout);
    gemm_proj<<<768, 256, 0, stream>>>(aout, projwb, proj_b, outp);
}

// Round 8
// 298.373 us; speedup vs baseline: 1.2264x; 1.2264x over previous
//
#include <hip/hip_runtime.h>
#include <cstdint>
#include <cstddef>

#define AS1 __attribute__((address_space(1)))
#define AS3 __attribute__((address_space(3)))

typedef float f32x4 __attribute__((ext_vector_type(4)));
typedef __bf16 bf16x8 __attribute__((ext_vector_type(8)));
typedef __bf16 bf16x4 __attribute__((ext_vector_type(4)));
typedef uint32_t u32x4 __attribute__((ext_vector_type(4)));

// async global->LDS, 16B per lane. LDS dest = wave-uniform base + lane*16.
__device__ __forceinline__ void async_cp16(void* lds, const void* g) {
    __builtin_amdgcn_global_load_lds((AS1 void*)(g), (AS3 void*)(lds), 16, 0, 0);
}

__device__ __forceinline__ bf16x8 frag_of(u32x4 u) {
    return __builtin_bit_cast(bf16x8, u);
}

// ---------------------------------------------------------------- weight cvt
// qkv_w rows permuted from interleaved (h,{q,k,v},d) to [q(768)|k(768)|v(768)]
__global__ __launch_bounds__(256)
void cvt_w(const float* __restrict__ qkvw, const float* __restrict__ projw,
           __bf16* __restrict__ qkvwb, __bf16* __restrict__ projwb) {
    int i = blockIdx.x * 256 + threadIdx.x;   // grid 2304*256 = 589824 exactly
    if (i < 442368) {                          // 2304 rows x 192 float4
        int row = i / 192, c4 = (i - row * 192) * 4;
        int t = (row >= 1536) ? 2 : (row >= 768 ? 1 : 0);
        int rem = row - t * 768;
        int hh = rem >> 6, d = rem & 63;
        int in_row = hh * 192 + t * 64 + d;
        float4 v = *(const float4*)(qkvw + (long)in_row * 768 + c4);
        bf16x4 o;
        o[0] = (__bf16)v.x; o[1] = (__bf16)v.y; o[2] = (__bf16)v.z; o[3] = (__bf16)v.w;
        *(bf16x4*)(qkvwb + (long)row * 768 + c4) = o;
    } else {
        int j = i - 442368;                    // 147456 float4 of proj_w
        float4 v = ((const float4*)projw)[j];
        bf16x4 o;
        o[0] = (__bf16)v.x; o[1] = (__bf16)v.y; o[2] = (__bf16)v.z; o[3] = (__bf16)v.w;
        ((bf16x4*)projwb)[j] = o;
    }
}

// ---------------------------------------------------------------- LayerNorm
__global__ __launch_bounds__(256)
void ln_kernel(const float* __restrict__ x, const float* __restrict__ w,
               const float* __restrict__ bsh, __bf16* __restrict__ xn) {
    const int lane = threadIdx.x & 63;
    const long row = (long)blockIdx.x * 4 + (threadIdx.x >> 6);
    const float4* xr = (const float4*)(x + row * 768);
    float4 v[3];
    v[0] = xr[lane]; v[1] = xr[lane + 64]; v[2] = xr[lane + 128];
    float s = 0.f, ss = 0.f;
#pragma unroll
    for (int i = 0; i < 3; ++i) {
        s  += v[i].x + v[i].y + v[i].z + v[i].w;
        ss += v[i].x * v[i].x + v[i].y * v[i].y + v[i].z * v[i].z + v[i].w * v[i].w;
    }
#pragma unroll
    for (int m = 1; m < 64; m <<= 1) { s += __shfl_xor(s, m); ss += __shfl_xor(ss, m); }
    const float mean = s * (1.f / 768.f);
    const float rstd = rsqrtf(ss * (1.f / 768.f) - mean * mean + 1e-5f);
    const float4* wv = (const float4*)w;
    const float4* bv = (const float4*)bsh;
    bf16x4* outp = (bf16x4*)(xn + row * 768);
#pragma unroll
    for (int i = 0; i < 3; ++i) {
        float4 wi = wv[lane + 64 * i], bi = bv[lane + 64 * i];
        bf16x4 o;
        o[0] = (__bf16)((v[i].x - mean) * rstd * wi.x + bi.x);
        o[1] = (__bf16)((v[i].y - mean) * rstd * wi.y + bi.y);
        o[2] = (__bf16)((v[i].z - mean) * rstd * wi.z + bi.z);
        o[3] = (__bf16)((v[i].w - mean) * rstd * wi.w + bi.w);
        outp[lane + 64 * i] = o;
    }
}

// ---------------------------------------------------------------- GEMM core
// 128x128 tile, BK=32, 4 waves. A+B staged in double-buffered LDS (2x16KB =
// 32KB -> 4 blocks/CU, the VGPR=68 occupancy cap). Counted vmcnt(4): stage(t)
// verified retired while stage(t+1) stays in flight; barrier (b) is preceded
// only by lgkmcnt(0) (free) - NO vmcnt drain in the main loop. stage(t+2)
// overwrites buf t only after barrier (b) proves all waves finished reading.
// Frag reads XOR-swizzled (swq = quad ^ ((l16>>1)&3), 2 lanes/bank = free),
// inverse swizzle pre-applied on the global source (global_load_lds is linear).
// (r7 lesson: per-wave direct-from-L2 B loads regressed 1.56x - the barrier
// convoy gates on slowest-wave private gathers; keep operands block-shared.)
// MODE 0: qk cols, swapped mfma -> packed (b,h,n,d) stores.
// MODE 2: v cols, normal mfma -> packed V^T (b,h,d,n) stores.
// MODE 1: proj, normal mfma -> fp32 out.
template <int MODE>
__device__ __forceinline__
void gemm_core(char* smem,
               const __bf16* __restrict__ A, const __bf16* __restrict__ Bw,
               const float* __restrict__ bias,
               __bf16* __restrict__ q_out, __bf16* __restrict__ k_out,
               __bf16* __restrict__ vt_out, float* __restrict__ f_out,
               long bm, long bn) {
    constexpr int K = 768;
    const int tid  = threadIdx.x;
    const int lane = tid & 63;
    const int quad = lane >> 4;
    const int l16  = lane & 15;
    const int wave = tid >> 6;
    const int wm = wave >> 1, wn = wave & 1;

    const __bf16* Ab = A  + bm * K;
    const __bf16* Bb = Bw + bn * K;

    const int e0 = tid, e1 = tid + 256;
    const int rA0 = e0 >> 2, c0 = ((e0 & 3) ^ ((e0 >> 3) & 3)) * 8;
    const int rA1 = e1 >> 2, c1 = ((e1 & 3) ^ ((e1 >> 3) & 3)) * 8;
    const int swq = quad ^ ((l16 >> 1) & 3);

    f32x4 acc[4][4] = {};

    auto stage = [&](int t) {
        char* base = smem + (t & 1) * 16384;
        const __bf16* As_ = Ab + t * 32;
        const __bf16* Bs_ = Bb + t * 32;
        async_cp16(base + e0 * 16,        As_ + (long)rA0 * K + c0);
        async_cp16(base + e1 * 16,        As_ + (long)rA1 * K + c1);
        async_cp16(base + 8192 + e0 * 16, Bs_ + (long)rA0 * K + c0);
        async_cp16(base + 8192 + e1 * 16, Bs_ + (long)rA1 * K + c1);
    };

    auto kstep = [&](int buf) {
        const u32x4* Av = (const u32x4*)(smem + buf * 16384);
        const u32x4* Bv = (const u32x4*)(smem + buf * 16384 + 8192);
        bf16x8 af[4], bfr[4];
#pragma unroll
        for (int t = 0; t < 4; ++t) {
            af[t]  = frag_of(Av[(wm * 64 + t * 16 + l16) * 4 + swq]);
            bfr[t] = frag_of(Bv[(wn * 64 + t * 16 + l16) * 4 + swq]);
        }
        __builtin_amdgcn_s_setprio(1);
#pragma unroll
        for (int i = 0; i < 4; ++i)
#pragma unroll
            for (int j = 0; j < 4; ++j) {
                if constexpr (MODE == 0)
                    acc[i][j] = __builtin_amdgcn_mfma_f32_16x16x32_bf16(bfr[j], af[i], acc[i][j], 0, 0, 0);
                else
                    acc[i][j] = __builtin_amdgcn_mfma_f32_16x16x32_bf16(af[i], bfr[j], acc[i][j], 0, 0, 0);
            }
        __builtin_amdgcn_s_setprio(0);
    };

    // prologue: 2 K-tiles in flight (8 loads/thread outstanding)
    stage(0); stage(1);
    for (int t = 0; t < 24; ++t) {
        // (a) stage(t) retired (stage(t+1) may stay in flight); all waves sync
        if (t < 23) { asm volatile("s_waitcnt vmcnt(4)" ::: "memory"); }
        else        { asm volatile("s_waitcnt vmcnt(0)" ::: "memory"); }
        __builtin_amdgcn_s_barrier();
        kstep(t & 1);
        // (b) all waves done reading buf t (lgkm already drained by MFMA use)
        asm volatile("s_waitcnt lgkmcnt(0)" ::: "memory");
        __builtin_amdgcn_s_barrier();
        if (t < 22) stage(t + 2);     // overwrite buf t, proven idle by (b)
    }

    if constexpr (MODE == 0) {
        // swapped: lane row = n (l16-based), 4 consecutive cols per quad
#pragma unroll
        for (int j = 0; j < 4; ++j) {
            int col0 = (int)bn + wn * 64 + j * 16 + quad * 4;   // < 1536
            int t  = col0 >= 768;
            int cc = col0 - t * 768;
            int h  = cc >> 6, d = cc & 63;
            int f  = h * 192 + t * 64 + d;                      // original feature id
            float4 bb = *(const float4*)(bias + f);
            __bf16* dst = t ? k_out : q_out;
#pragma unroll
            for (int i = 0; i < 4; ++i) {
                long row = bm + wm * 64 + i * 16 + l16;
                long b   = row >> 10;
                long n   = row & 1023;
                bf16x4 pk;
                pk[0] = (__bf16)(acc[i][j][0] + bb.x);
                pk[1] = (__bf16)(acc[i][j][1] + bb.y);
                pk[2] = (__bf16)(acc[i][j][2] + bb.z);
                pk[3] = (__bf16)(acc[i][j][3] + bb.w);
                *(bf16x4*)(dst + ((b * 12 + h) * 1024 + n) * 64 + d) = pk;
            }
        }
    } else if constexpr (MODE == 2) {
        // normal: lane col = d (l16-based), 4 consecutive rows (n) per quad
#pragma unroll
        for (int j = 0; j < 4; ++j) {
            int cv = (int)bn - 1536 + wn * 64 + j * 16 + l16;
            int h  = cv >> 6, d = cv & 63;
            float bv = bias[h * 192 + 128 + d];
#pragma unroll
            for (int i = 0; i < 4; ++i) {
                long row0 = bm + wm * 64 + i * 16 + quad * 4;
                long b    = row0 >> 10;
                long n0   = row0 & 1023;
                bf16x4 pk;
                pk[0] = (__bf16)(acc[i][j][0] + bv);
                pk[1] = (__bf16)(acc[i][j][1] + bv);
                pk[2] = (__bf16)(acc[i][j][2] + bv);
                pk[3] = (__bf16)(acc[i][j][3] + bv);
                *(bf16x4*)(vt_out + ((b * 12 + h) * 64 + d) * 1024 + n0) = pk;
            }
        }
    } else {
#pragma unroll
        for (int i = 0; i < 4; ++i) {
#pragma unroll
            for (int r = 0; r < 4; ++r) {
                long row = bm + wm * 64 + i * 16 + quad * 4 + r;
#pragma unroll
                for (int j = 0; j < 4; ++j) {
                    int col = (int)bn + wn * 64 + j * 16 + l16;
                    f_out[row * 768 + col] = acc[i][j][r] + bias[col];
                }
            }
        }
    }
}

// XCD-aware decode: all blocks sharing one A-tile (by) land on one XCD.
__global__ __launch_bounds__(256, 4)
void gemm_qkv(const __bf16* __restrict__ A, const __bf16* __restrict__ Bw,
              const float* __restrict__ bias, __bf16* __restrict__ qb,
              __bf16* __restrict__ kb, __bf16* __restrict__ vtb) {
    __shared__ __align__(16) char smem[32768];   // dbuf x (A 8K + B 8K)
    int blk  = blockIdx.x;            // grid 2304
    int xcd  = blk & 7;
    int rest = blk >> 3;              // 0..287
    int bx   = rest % 18;
    int byg  = rest / 18;             // 0..15
    long by  = xcd + 8 * byg;         // by % 8 == xcd
    if (bx < 12)
        gemm_core<0>(smem, A, Bw, bias, qb, kb, nullptr, nullptr, by * 128, (long)bx * 128);
    else
        gemm_core<2>(smem, A, Bw, bias, nullptr, nullptr, vtb, nullptr, by * 128, (long)bx * 128);
}

__global__ __launch_bounds__(256, 4)
void gemm_proj(const __bf16* __restrict__ A, const __bf16* __restrict__ Bw,
               const float* __restrict__ bias, float* __restrict__ out) {
    __shared__ __align__(16) char smem[32768];
    int blk  = blockIdx.x;            // grid 768
    int xcd  = blk & 7;
    int rest = blk >> 3;              // 0..95
    int bx   = rest % 6;
    int byg  = rest / 6;              // 0..15
    long by  = xcd + 8 * byg;
    gemm_core<1>(smem, A, Bw, bias, nullptr, nullptr, nullptr, out,
                 by * 128, (long)bx * 128);
}

// ---------------------------------------------------------------- flash attention
// 256 thr / 4 waves, 128-row q-tile, 32 q-rows/wave (g=0,1 groups, K/V frag
// reuse across g). KVBLK=32: one k-tile = exactly one y-row (dy wave-uniform).
// LDS = 28KB (K dbuf 8K + V^T dbuf 8K + P 8K + bias 4K).
// Row widths chosen for bank-freedom: K/Q rows 128B (8 slots, sw=l16&7);
// P/V rows 64B with chunk swizzle rho(row)=(row>>1)&3 -> every b128 read and
// b64 write lands 2 lanes/bank (free). P goes through LDS.
// K/V double-buffered; prefetch kt+1 before compute kt; ONE barrier per tile.
__global__ __launch_bounds__(256, 4)
void attn_kernel(const __bf16* __restrict__ Q, const __bf16* __restrict__ Kb,
                 const __bf16* __restrict__ Vt, const float* __restrict__ biases,
                 __bf16* __restrict__ out) {
    // [0,8K): K dbuf 2x4K | [8K,16K): V^T dbuf 2x4K | [16K,24K): P per-wave 2K
    // [24K,28K): bias row f32 * log2(e).  Q stages through [0,16K) at startup.
    __shared__ __align__(16) char smem[28672];
    float* brow = (float*)(smem + 24576);

    const int tid  = threadIdx.x;
    const int lane = tid & 63;
    const int wave = tid >> 6;        // 0..3
    const int quad = lane >> 4;
    const int l16  = lane & 15;
    const int sw   = l16 & 7;         // 8-slot rows (Q, K)
    const int swp  = (l16 >> 1) & 3;  // 4-slot rows (P, V)

    int blk  = blockIdx.x;            // grid 1536
    int xcd  = blk & 7;
    int rest = blk >> 3;              // 0..191
    int qt   = rest & 7;              // 0..7 (128-row q tiles)
    int bhg  = rest >> 3;             // 0..23
    int bh_i = xcd + 8 * bhg;         // 0..191, bh % 8 == xcd
    int b    = bh_i / 12;
    int h    = bh_i - b * 12;

    const long bh = bh_i;
    const __bf16* Qg  = Q  + (bh * 1024 + qt * 128) * 64;
    const __bf16* Kg  = Kb + bh * 1024 * 64;
    const __bf16* Vtg = Vt + bh * 64 * 1024;

    // staging indices (kt-invariant)
    const int rk = tid >> 3;                    // K: row 0..31 (128B rows)
    const int ck = (tid & 7) ^ (rk & 7);
    const int rv = tid >> 2;                    // V: row 0..63 (64B rows)
    const int cv = (tid & 3) ^ ((tid >> 3) & 3);

    // prologue: bias row + Q (through K/V region) -------------------------
    {
        const float LOG2E = 1.4426950408889634f;
        float4 v = ((const float4*)(biases + (long)h * 1024))[tid];
        float4 o; o.x = v.x * LOG2E; o.y = v.y * LOG2E;
        o.z = v.z * LOG2E; o.w = v.w * LOG2E;
        ((float4*)brow)[tid] = o;
    }
#pragma unroll
    for (int j = 0; j < 4; ++j) {
        int e = tid + 256 * j;
        int r = e >> 3, c = (e & 7) ^ (r & 7);
        async_cp16(smem + e * 16, Qg + r * 64 + c * 8);
    }
    __syncthreads();                  // Q resident (barrier drains vmcnt)

    bf16x8 aq[2][2];
    {
        const u32x4* Qv = (const u32x4*)smem;
#pragma unroll
        for (int g = 0; g < 2; ++g) {
            int qrow = wave * 32 + g * 16 + l16;
            aq[g][0] = frag_of(Qv[qrow * 8 + (quad ^ sw)]);
            aq[g][1] = frag_of(Qv[qrow * 8 + ((quad + 4) ^ sw)]);
        }
    }
    __syncthreads();                  // all waves done reading Q
    async_cp16(smem + tid * 16,        Kg  + rk * 64   + ck * 8);   // K0
    async_cp16(smem + 8192 + tid * 16, Vtg + rv * 1024 + cv * 8);   // V0
    __syncthreads();                  // K0/V0 resident

    // relative-position tables (kt-invariant); g==nt -> pdx00, g<nt -> pdx01,
    // g>nt -> pdx10
    const int yq = 4 * qt + wave;
    int pdx00[4], pdx01[4], pdx10[4];
#pragma unroll
    for (int r = 0; r < 4; ++r) {
        int d0 = l16 - (quad * 4 + r);
        pdx00[r] = d0 < 0 ? -d0 : d0;
        pdx01[r] = 16 - d0;
        pdx10[r] = 16 + d0;
    }

    const float SSCALE = 0.125f * 1.4426950408889634f;
    float lacc[2] = {0.f, 0.f};
    f32x4 o[2][4] = {};
    char* Pw = smem + 16384 + wave * 2048;      // 32 rows x 64B, per-wave
    const int hb = (quad & 1) * 8;
    const int pslotw = (quad >> 1);             // write chunk sub-index base

    for (int kt = 0; kt < 32; ++kt) {
        const int cb = kt & 1;
        if (kt < 31) {
            const int nb = cb ^ 1;
            async_cp16(smem + nb * 4096 + tid * 16,
                       Kg + (kt + 1) * 2048 + rk * 64 + ck * 8);
            async_cp16(smem + 8192 + nb * 4096 + tid * 16,
                       Vtg + (kt + 1) * 32 + rv * 1024 + cv * 8);
        }

        // S^T = K * Q^T : s[g][nt][r] = S[q=g*16+l16][k = kt*32+nt*16+quad*4+r]
        f32x4 s[2][2];
        const u32x4* Kv = (const u32x4*)(smem + cb * 4096);
#pragma unroll
        for (int nt = 0; nt < 2; ++nt) {
            int krow = nt * 16 + l16;
            bf16x8 k0 = frag_of(Kv[krow * 8 + (quad ^ sw)]);
            bf16x8 k1 = frag_of(Kv[krow * 8 + ((quad + 4) ^ sw)]);
#pragma unroll
            for (int g = 0; g < 2; ++g) {
                f32x4 z = {0.f, 0.f, 0.f, 0.f};
                z = __builtin_amdgcn_mfma_f32_16x16x32_bf16(k0, aq[g][0], z, 0, 0, 0);
                z = __builtin_amdgcn_mfma_f32_16x16x32_bf16(k1, aq[g][1], z, 0, 0, 0);
                s[g][nt] = z;
            }
        }

        // softmax + P store (per-wave LDS, rho-swizzled 64B rows)
        int dyv = yq - kt; dyv = dyv < 0 ? -dyv : dyv;
        const float* br = brow + dyv * 32;
#pragma unroll
        for (int g = 0; g < 2; ++g) {
#pragma unroll
            for (int nt = 0; nt < 2; ++nt) {
                const int* pdx = (g == nt) ? pdx00 : (g ? pdx10 : pdx01);
                bf16x4 pk;
#pragma unroll
                for (int r = 0; r < 4; ++r) {
                    float p = __builtin_amdgcn_exp2f(s[g][nt][r] * SSCALE + br[pdx[r]]);
                    lacc[g] += p;
                    pk[r] = (__bf16)p;
                }
                int slot = (nt * 2 + pslotw) ^ swp;
                *(bf16x4*)(Pw + (g * 16 + l16) * 64 + slot * 16 + hb) = pk;
            }
        }

        // P read (B-frags) + O^T = V^T * P^T
        bf16x8 bp[2];
#pragma unroll
        for (int g = 0; g < 2; ++g)
            bp[g] = frag_of(*(const u32x4*)(Pw + (g * 16 + l16) * 64 + ((quad ^ swp) << 4)));
        const char* Vb = smem + 8192 + cb * 4096;
#pragma unroll
        for (int dt = 0; dt < 4; ++dt) {
            bf16x8 vf = frag_of(*(const u32x4*)(Vb + (dt * 16 + l16) * 64 + ((quad ^ swp) << 4)));
#pragma unroll
            for (int g = 0; g < 2; ++g)
                o[g][dt] = __builtin_amdgcn_mfma_f32_16x16x32_bf16(vf, bp[g], o[g][dt], 0, 0, 0);
        }

        // single barrier per tile: drains prefetch (vmcnt) AFTER compute and
        // protects buffer cb from being overwritten next iteration
        __syncthreads();
    }

    // deferred row-sum: combine the 4 quads holding the same q-row
#pragma unroll
    for (int g = 0; g < 2; ++g) {
        float la = lacc[g];
        la += __shfl_xor(la, 16);
        la += __shfl_xor(la, 32);
        const float rl = 1.f / la;
        const long n = qt * 128 + wave * 32 + g * 16 + l16;
        __bf16* op = out + ((long)b * 1024 + n) * 768 + h * 64 + quad * 4;
#pragma unroll
        for (int dt = 0; dt < 4; ++dt) {
            bf16x4 ov;
            ov[0] = (__bf16)(o[g][dt][0] * rl);
            ov[1] = (__bf16)(o[g][dt][1] * rl);
            ov[2] = (__bf16)(o[g][dt][2] * rl);
            ov[3] = (__bf16)(o[g][dt][3] * rl);
            *(bf16x4*)(op + dt * 16) = ov;
        }
    }
}

// ---------------------------------------------------------------- launch
extern "C" void kernel_launch(void* const* d_in, const int* in_sizes, int n_in,
                              void* d_out, int out_size, void* d_ws, size_t ws_size,
                              hipStream_t stream) {
    (void)in_sizes; (void)n_in; (void)out_size; (void)ws_size;
    const float* x      = (const float*)d_in[0];
    const float* ln_w   = (const float*)d_in[1];
    const float* ln_b   = (const float*)d_in[2];
    const float* qkv_w  = (const float*)d_in[3];
    const float* qkv_b  = (const float*)d_in[4];
    const float* proj_w = (const float*)d_in[5];
    const float* proj_b = (const float*)d_in[6];
    const float* ab     = (const float*)d_in[7];
    float* outp = (float*)d_out;

    char* ws = (char*)d_ws;
    __bf16* xn     = (__bf16*)(ws);               // reused as attn output
    __bf16* aout   = (__bf16*)(ws);
    __bf16* qkvwb  = (__bf16*)(ws + 25165824);
    __bf16* projwb = (__bf16*)(ws + 28704768);
    __bf16* qb     = (__bf16*)(ws + 29884416);
    __bf16* kb     = (__bf16*)(ws + 55050240);
    __bf16* vtb    = (__bf16*)(ws + 80216064);    // V^T (b,h,d,n), direct from GEMM

    cvt_w<<<2304, 256, 0, stream>>>(qkv_w, proj_w, qkvwb, projwb);
    ln_kernel<<<4096, 256, 0, stream>>>(x, ln_w, ln_b, xn);
    gemm_qkv<<<2304, 256, 0, stream>>>(xn, qkvwb, qkv_b, qb, kb, vtb);
    attn_kernel<<<1536, 256, 0, stream>>>(qb, kb, vtb, ab, aout);
    gemm_proj<<<768, 256, 0, stream>>>(aout, projwb, proj_b, outp);
}